// Round 2
// baseline (3792.274 us; speedup 1.0000x reference)
//
#include <hip/hip_runtime.h>
#include <hip/hip_cooperative_groups.h>

#define HH 2048
#define WW 2048
#define NPX (HH*WW)
#define INFV 1e30f
#define TILE 64
#define NTX 32
#define NTILES 1024
#define REP 4

namespace cg = cooperative_groups;

// ---------- shared math (pinned rounding so every pass computes identical fr) ----------
__device__ __forceinline__ float sobel_at(const float* __restrict__ g, int y, int x){
  float a00,a01,a02,a10,a12,a20,a21,a22;
  if (y>0 && y<HH-1 && x>0 && x<WW-1){
    const float* p = g + (size_t)(y-1)*WW + x;
    a00=p[-1]; a01=p[0]; a02=p[1];
    p += WW;   a10=p[-1];          a12=p[1];
    p += WW;   a20=p[-1]; a21=p[0]; a22=p[1];
  } else {
    auto at=[&](int yy,int xx)->float{
      return (yy<0||yy>=HH||xx<0||xx>=WW)?0.0f:g[(size_t)yy*WW+xx];
    };
    a00=at(y-1,x-1); a01=at(y-1,x); a02=at(y-1,x+1);
    a10=at(y,  x-1);                a12=at(y,  x+1);
    a20=at(y+1,x-1); a21=at(y+1,x); a22=at(y+1,x+1);
  }
  float gx = __fadd_rn(__fadd_rn(__fsub_rn(a02,a00), __fmul_rn(2.0f,__fsub_rn(a12,a10))), __fsub_rn(a22,a20));
  float gy = __fadd_rn(__fadd_rn(__fsub_rn(a20,a00), __fmul_rn(2.0f,__fsub_rn(a21,a01))), __fsub_rn(a22,a02));
  return sqrtf(__fadd_rn(__fmul_rn(gx,gx),__fmul_rn(gy,gy)));
}

// ---------- gray ----------
__global__ void gray_kernel(const float* __restrict__ img, float* __restrict__ gray){
  const float* R=img; const float* G=img+NPX; const float* B=img+2*(size_t)NPX;
  for (int i=blockIdx.x*blockDim.x+threadIdx.x; i<NPX; i+=gridDim.x*blockDim.x){
    gray[i] = __fadd_rn(__fadd_rn(__fmul_rn(0.2989f,R[i]),__fmul_rn(0.587f,G[i])),__fmul_rn(0.114f,B[i]));
  }
}

// ---------- sobel once, cached to fr; level-1 histogram fused ----------
__global__ void sobel_hist1(const float* __restrict__ gray, float* __restrict__ fr,
                            unsigned* __restrict__ hist){
  __shared__ unsigned h[4*2048];
  for (int i=threadIdx.x;i<4*2048;i+=blockDim.x) h[i]=0;
  __syncthreads();
  const int rep=(threadIdx.x&3)*2048;
  for (int i=blockIdx.x*blockDim.x+threadIdx.x; i<NPX; i+=gridDim.x*blockDim.x){
    int y=i>>11, x=i&(WW-1);
    float f=sobel_at(gray,y,x);
    fr[i]=f;
    unsigned key=__float_as_uint(f);
    atomicAdd(&h[rep+(key>>21)],1u);
  }
  __syncthreads();
  for (int i=threadIdx.x;i<2048;i+=blockDim.x){
    unsigned s=h[i]+h[i+2048]+h[i+4096]+h[i+6144];
    if (s) atomicAdd(&hist[i],s);
  }
}

__global__ void hist_l2(const float* __restrict__ fr, const unsigned* __restrict__ sel1,
                        unsigned* __restrict__ hist2){
  __shared__ unsigned h[4*2048];
  __shared__ unsigned sb[4];
  if (threadIdx.x<4) sb[threadIdx.x]=sel1[threadIdx.x];
  for (int i=threadIdx.x;i<4*2048;i+=blockDim.x) h[i]=0;
  __syncthreads();
  for (int i=blockIdx.x*blockDim.x+threadIdx.x; i<NPX; i+=gridDim.x*blockDim.x){
    unsigned key=__float_as_uint(fr[i]);
    unsigned b=key>>21, sub=(key>>10)&0x7FFu;
    #pragma unroll
    for (int k=0;k<4;++k) if (b==sb[k]) atomicAdd(&h[k*2048+sub],1u);
  }
  __syncthreads();
  for (int i=threadIdx.x;i<4*2048;i+=blockDim.x){ unsigned s=h[i]; if (s) atomicAdd(&hist2[i],s); }
}

__global__ void hist_l3(const float* __restrict__ fr, const unsigned* __restrict__ sel1,
                        const unsigned* __restrict__ sel2, unsigned* __restrict__ hist3){
  __shared__ unsigned h[4*1024];
  __shared__ unsigned pf[4];
  if (threadIdx.x<4) pf[threadIdx.x]=(sel1[threadIdx.x]<<11)|sel2[threadIdx.x];
  for (int i=threadIdx.x;i<4*1024;i+=blockDim.x) h[i]=0;
  __syncthreads();
  for (int i=blockIdx.x*blockDim.x+threadIdx.x; i<NPX; i+=gridDim.x*blockDim.x){
    unsigned key=__float_as_uint(fr[i]);
    unsigned p22=key>>10, sub=key&0x3FFu;
    #pragma unroll
    for (int k=0;k<4;++k) if (p22==pf[k]) atomicAdd(&h[k*1024+sub],1u);
  }
  __syncthreads();
  for (int i=threadIdx.x;i<4*1024;i+=blockDim.x){ unsigned s=h[i]; if (s) atomicAdd(&hist3[i],s); }
}

// ranks: floor(0.9825*(n-1))=4120902, floor(0.9925*(n-1))=4162845 (and +1 each)
__global__ void scan_l1(const unsigned* __restrict__ hist, unsigned* __restrict__ sel1,
                        unsigned* __restrict__ rem1){
  __shared__ unsigned part[1024];
  const int t=threadIdx.x;
  unsigned a=hist[2*t], b=hist[2*t+1];
  part[t]=a+b; __syncthreads();
  for (int off=1;off<1024;off<<=1){
    unsigned add=(t>=off)?part[t-off]:0u; __syncthreads();
    part[t]+=add; __syncthreads();
  }
  unsigned before=(t>0)?part[t-1]:0u;
  const unsigned R[4]={4120902u,4120903u,4162845u,4162846u};
  unsigned cum=before;
  #pragma unroll
  for (int i=0;i<4;++i) if (R[i]>=cum && R[i]<cum+a){ sel1[i]=2*t;   rem1[i]=R[i]-cum; }
  cum+=a;
  #pragma unroll
  for (int i=0;i<4;++i) if (R[i]>=cum && R[i]<cum+b){ sel1[i]=2*t+1; rem1[i]=R[i]-cum; }
}

__global__ void scan_l2(const unsigned* __restrict__ hist2, const unsigned* __restrict__ rem1,
                        unsigned* __restrict__ sel2, unsigned* __restrict__ rem2){
  __shared__ unsigned part[1024];
  const int t=threadIdx.x;
  for (int i=0;i<4;++i){
    const unsigned* hh=hist2+i*2048;
    unsigned a=hh[2*t], b=hh[2*t+1];
    part[t]=a+b; __syncthreads();
    for (int off=1;off<1024;off<<=1){
      unsigned add=(t>=off)?part[t-off]:0u; __syncthreads();
      part[t]+=add; __syncthreads();
    }
    unsigned before=(t>0)?part[t-1]:0u;
    unsigned r=rem1[i], cum=before;
    if (r>=cum && r<cum+a){ sel2[i]=2*t;   rem2[i]=r-cum; }
    cum+=a;
    if (r>=cum && r<cum+b){ sel2[i]=2*t+1; rem2[i]=r-cum; }
    __syncthreads();
  }
}

__global__ void scan_l3(const unsigned* __restrict__ hist3, const unsigned* __restrict__ sel1,
                        const unsigned* __restrict__ sel2, const unsigned* __restrict__ rem2,
                        float* __restrict__ scal){
  __shared__ unsigned part[1024];
  __shared__ float vals[4];
  const int t=threadIdx.x;
  for (int i=0;i<4;++i){
    unsigned c=hist3[i*1024+t];
    part[t]=c; __syncthreads();
    for (int off=1;off<1024;off<<=1){
      unsigned add=(t>=off)?part[t-off]:0u; __syncthreads();
      part[t]+=add; __syncthreads();
    }
    unsigned before=(t>0)?part[t-1]:0u;
    unsigned r=rem2[i];
    if (r>=before && r<before+c){
      unsigned key=(sel1[i]<<21)|(sel2[i]<<10)|(unsigned)t;
      vals[i]=__uint_as_float(key);
    }
    __syncthreads();
  }
  if (t==0){
    scal[0]=__fadd_rn(__fmul_rn(vals[0],0.25f),__fmul_rn(vals[1],0.75f));
    scal[1]=__fadd_rn(__fmul_rn(vals[2],0.25f),__fmul_rn(vals[3],0.75f));
  }
}

// ---------- markers -> initial costs (fr aliases c1out; per-element read-then-write) ----------
__global__ void init_cost(const float* __restrict__ gray, const float* frbuf,
                          const float* __restrict__ scal,
                          float* c1out, float* __restrict__ c2out){
  const float qlo=scal[0], qhi=scal[1];
  for (int i=blockIdx.x*blockDim.x+threadIdx.x; i<NPX; i+=gridDim.x*blockDim.x){
    float f=frbuf[i];
    float g=gray[i];
    bool m1 = (f<=qlo);
    bool m2 = (!m1) && (f>=qhi);
    c1out[i] = m1 ? g : INFV;
    c2out[i] = m2 ? g : INFV;
  }
}

// ---------- cooperative fixed-point solver ----------
struct TileSh {
  float Ht1[64],Hb1[64],Hl1[64],Hr1[64];
  float Ht2[64],Hb2[64],Hl2[64],Hr2[64];
  float Br1[6][64], Br2[6][64];   // boundary rows 15,16,31,32,47,48
  int bflag, banyf, sneed;
};

__device__ bool relax_tile(int tile, int it, int rep,
                           float* __restrict__ c1, float* __restrict__ c2,
                           const float* __restrict__ gray,
                           TileSh& T, int* dr, int* dw)
{
  const int tid=threadIdx.x;
  __syncthreads();            // protect LDS reuse across calls
  if (tid==0){
    const int ty=tile>>5, tx=tile&31;
    int need=0;
    if (rep==0){
      need=(it==0)?1:0;
      if(!need)        need=__hip_atomic_load(&dr[tile],__ATOMIC_RELAXED,__HIP_MEMORY_SCOPE_AGENT);
      if(!need&&ty>0)  need=__hip_atomic_load(&dr[tile-NTX],__ATOMIC_RELAXED,__HIP_MEMORY_SCOPE_AGENT);
      if(!need&&ty<31) need=__hip_atomic_load(&dr[tile+NTX],__ATOMIC_RELAXED,__HIP_MEMORY_SCOPE_AGENT);
      if(!need&&tx>0)  need=__hip_atomic_load(&dr[tile-1],__ATOMIC_RELAXED,__HIP_MEMORY_SCOPE_AGENT);
      if(!need&&tx<31) need=__hip_atomic_load(&dr[tile+1],__ATOMIC_RELAXED,__HIP_MEMORY_SCOPE_AGENT);
    } else {
      if(ty>0)         need=__hip_atomic_load(&dw[tile-NTX],__ATOMIC_RELAXED,__HIP_MEMORY_SCOPE_AGENT);
      if(!need&&ty<31) need=__hip_atomic_load(&dw[tile+NTX],__ATOMIC_RELAXED,__HIP_MEMORY_SCOPE_AGENT);
      if(!need&&tx>0)  need=__hip_atomic_load(&dw[tile-1],__ATOMIC_RELAXED,__HIP_MEMORY_SCOPE_AGENT);
      if(!need&&tx<31) need=__hip_atomic_load(&dw[tile+1],__ATOMIC_RELAXED,__HIP_MEMORY_SCOPE_AGENT);
    }
    T.sneed=need; T.bflag=0; T.banyf=0;
  }
  __syncthreads();
  if (!T.sneed) return false;

  const int col=tid&63, rg=tid>>6;
  const int ty=tile>>5, tx=tile&31;
  const int by=ty*TILE, bx=tx*TILE;

  float v1[16], v2[16], g[16];
  {
    int base=(by+rg*16)*WW+bx+col;
    #pragma unroll
    for (int j=0;j<16;++j){
      v1[j]=c1[base]; v2[j]=c2[base]; g[j]=gray[base]; base+=WW;
    }
  }
  if (rg==0){
    T.Ht1[col]=(by>0)?c1[(by-1)*WW+bx+col]:INFV;
    T.Ht2[col]=(by>0)?c2[(by-1)*WW+bx+col]:INFV;
  } else if (rg==1){
    T.Hb1[col]=(by+TILE<HH)?c1[(by+TILE)*WW+bx+col]:INFV;
    T.Hb2[col]=(by+TILE<HH)?c2[(by+TILE)*WW+bx+col]:INFV;
  } else if (rg==2){
    T.Hl1[col]=(bx>0)?c1[(by+col)*WW+bx-1]:INFV;
    T.Hl2[col]=(bx>0)?c2[(by+col)*WW+bx-1]:INFV;
  } else {
    T.Hr1[col]=(bx+TILE<WW)?c1[(by+col)*WW+bx+TILE]:INFV;
    T.Hr2[col]=(bx+TILE<WW)?c2[(by+col)*WW+bx+TILE]:INFV;
  }
  __syncthreads();

  for (int cyc=0; cyc<512; ++cyc){
    bool ch=false;
    // vertical sweeps: group k down-sweep overlapped with group 3-k up-sweep
    #pragma unroll 1
    for (int k=0;k<4;++k){
      if (rg==k){
        float p1=(k==0)?T.Ht1[col]:T.Br1[2*k-2][col];
        float p2=(k==0)?T.Ht2[col]:T.Br2[2*k-2][col];
        #pragma unroll
        for (int j=0;j<16;++j){
          float n1=fminf(v1[j],fmaxf(p1,g[j])); if(n1<v1[j]){v1[j]=n1;ch=true;} p1=n1;
          float n2=fminf(v2[j],fmaxf(p2,g[j])); if(n2<v2[j]){v2[j]=n2;ch=true;} p2=n2;
        }
        if (k<3){ T.Br1[2*k][col]=p1; T.Br2[2*k][col]=p2; }
      }
      const int u=3-k;
      if (rg==u){
        float p1=(u==3)?T.Hb1[col]:T.Br1[2*u+1][col];
        float p2=(u==3)?T.Hb2[col]:T.Br2[2*u+1][col];
        #pragma unroll
        for (int j=15;j>=0;--j){
          float n1=fminf(v1[j],fmaxf(p1,g[j])); if(n1<v1[j]){v1[j]=n1;ch=true;} p1=n1;
          float n2=fminf(v2[j],fmaxf(p2,g[j])); if(n2<v2[j]){v2[j]=n2;ch=true;} p2=n2;
        }
        if (u>0){ T.Br1[2*u-1][col]=p1; T.Br2[2*u-1][col]=p2; }
      }
      __syncthreads();
    }
    // horizontal sweeps via clamp-compose scans (wave-local; probe skips clean rows)
    #pragma unroll 1
    for (int j=0;j<16;++j){
      const int r=rg*16+j;
      // L -> R
      {
        float h1=T.Hl1[r], h2=T.Hl2[r];
        float a1=__shfl_up(v1[j],1u); if(col==0) a1=h1;
        float a2=__shfl_up(v2[j],1u); if(col==0) a2=h2;
        float t1=fminf(v1[j],fmaxf(a1,g[j]));
        float t2=fminf(v2[j],fmaxf(a2,g[j]));
        if (__any((t1<v1[j])||(t2<v2[j]))){
          float lo1=g[j],hi1=v1[j],lo2=g[j],hi2=v2[j];
          #pragma unroll
          for (int d=1;d<64;d<<=1){
            float ql1=__shfl_up(lo1,(unsigned)d), qh1=__shfl_up(hi1,(unsigned)d);
            float ql2=__shfl_up(lo2,(unsigned)d), qh2=__shfl_up(hi2,(unsigned)d);
            if (col>=d){
              hi1=fminf(hi1,fmaxf(lo1,qh1)); lo1=fmaxf(lo1,ql1);
              hi2=fminf(hi2,fmaxf(lo2,qh2)); lo2=fmaxf(lo2,ql2);
            }
          }
          float n1=fminf(hi1,fmaxf(lo1,h1));
          float n2=fminf(hi2,fmaxf(lo2,h2));
          if(n1<v1[j]){v1[j]=n1;ch=true;}
          if(n2<v2[j]){v2[j]=n2;ch=true;}
        }
      }
      // R -> L
      {
        float h1=T.Hr1[r], h2=T.Hr2[r];
        float a1=__shfl_down(v1[j],1u); if(col==63) a1=h1;
        float a2=__shfl_down(v2[j],1u); if(col==63) a2=h2;
        float t1=fminf(v1[j],fmaxf(a1,g[j]));
        float t2=fminf(v2[j],fmaxf(a2,g[j]));
        if (__any((t1<v1[j])||(t2<v2[j]))){
          float lo1=g[j],hi1=v1[j],lo2=g[j],hi2=v2[j];
          #pragma unroll
          for (int d=1;d<64;d<<=1){
            float ql1=__shfl_down(lo1,(unsigned)d), qh1=__shfl_down(hi1,(unsigned)d);
            float ql2=__shfl_down(lo2,(unsigned)d), qh2=__shfl_down(hi2,(unsigned)d);
            if (col+d<64){
              hi1=fminf(hi1,fmaxf(lo1,qh1)); lo1=fmaxf(lo1,ql1);
              hi2=fminf(hi2,fmaxf(lo2,qh2)); lo2=fmaxf(lo2,ql2);
            }
          }
          float n1=fminf(hi1,fmaxf(lo1,h1));
          float n2=fminf(hi2,fmaxf(lo2,h2));
          if(n1<v1[j]){v1[j]=n1;ch=true;}
          if(n2<v2[j]){v2[j]=n2;ch=true;}
        }
      }
    }
    if (ch){ T.bflag=1; T.banyf=1; }
    __syncthreads();
    int f=T.bflag;
    __syncthreads();
    if (tid==0) T.bflag=0;
    if (!f) break;
  }
  __syncthreads();
  bool bc=(T.banyf!=0);
  if (bc){
    int base=(by+rg*16)*WW+bx+col;
    #pragma unroll
    for (int j=0;j<16;++j){ c1[base]=v1[j]; c2[base]=v2[j]; base+=WW; }
    if (tid==0) __hip_atomic_store(&dw[tile],1,__ATOMIC_RELAXED,__HIP_MEMORY_SCOPE_AGENT);
  }
  return bc;
}

__global__ void __launch_bounds__(256,4)
ws_solve(float* __restrict__ c1, float* __restrict__ c2, const float* __restrict__ gray,
         int* flags, int* dirty0, int* dirty1)
{
  __shared__ TileSh T;
  cg::grid_group grid = cg::this_grid();
  const int tid=threadIdx.x;
  for (int it=0; it<1024; ++it){
    int* dr=(it&1)?dirty1:dirty0;
    int* dw=(it&1)?dirty0:dirty1;
    bool passch=false;
    for (int rep=0; rep<REP; ++rep){
      for (int tile=blockIdx.x; tile<NTILES; tile+=gridDim.x)
        passch |= relax_tile(tile,it,rep,c1,c2,gray,T,dr,dw);
    }
    if (tid==0 && passch) atomicOr(&flags[it&1],1);
    __threadfence();
    grid.sync();
    int ch=__hip_atomic_load(&flags[it&1],__ATOMIC_RELAXED,__HIP_MEMORY_SCOPE_AGENT);
    if (blockIdx.x==0 && tid==0)
      __hip_atomic_store(&flags[(it+1)&1],0,__ATOMIC_RELAXED,__HIP_MEMORY_SCOPE_AGENT);
    for (int t2=blockIdx.x*blockDim.x+tid; t2<NTILES; t2+=gridDim.x*blockDim.x)
      __hip_atomic_store(&dr[t2],0,__ATOMIC_RELAXED,__HIP_MEMORY_SCOPE_AGENT);
    __threadfence();
    grid.sync();
    if (!ch) break;
  }
}

// ---------- output (c2 lives in d_out; rewrite in place) ----------
__global__ void out_kernel(const float* __restrict__ c1, float* o){
  for (int i=blockIdx.x*blockDim.x+threadIdx.x; i<NPX; i+=gridDim.x*blockDim.x){
    o[i] = (o[i] < c1[i]) ? 1.0f : 0.0f;
  }
}

extern "C" void kernel_launch(void* const* d_in, const int* in_sizes, int n_in,
                              void* d_out, int out_size, void* d_ws, size_t ws_size,
                              hipStream_t stream)
{
  const float* img=(const float*)d_in[0];
  float* out=(float*)d_out;
  char* wsb=(char*)d_ws;
  float* gray=(float*)wsb;
  float* c1  =(float*)(wsb + (size_t)NPX*4);   // doubles as fr cache before init_cost
  unsigned* meta=(unsigned*)(wsb + (size_t)NPX*8);
  float* c2 = out;   // reuse output buffer as c2 scratch (fully rewritten each launch)

  unsigned* hist1=meta;            // 2048
  unsigned* hist2=meta+2048;       // 4*2048
  unsigned* hist3=meta+10240;      // 4*1024
  unsigned* sel1 =meta+14336;
  unsigned* rem1 =meta+14340;
  unsigned* sel2 =meta+14344;
  unsigned* rem2 =meta+14348;
  float*    scal =(float*)(meta+14352);   // 2
  int*      flags=(int*)(meta+14354);     // 2
  int*      dirty0=(int*)(meta+14356);    // 1024
  int*      dirty1=(int*)(meta+15380);    // 1024  -> total 16404 u32

  hipMemsetAsync(meta, 0, 16404*sizeof(unsigned), stream);
  hipLaunchKernelGGL(gray_kernel, dim3(4096), dim3(256), 0, stream, img, gray);
  hipLaunchKernelGGL(sobel_hist1, dim3(1024), dim3(256), 0, stream, gray, c1, hist1);
  hipLaunchKernelGGL(scan_l1, dim3(1), dim3(1024), 0, stream, hist1, sel1, rem1);
  hipLaunchKernelGGL(hist_l2, dim3(1024), dim3(256), 0, stream, c1, sel1, hist2);
  hipLaunchKernelGGL(scan_l2, dim3(1), dim3(1024), 0, stream, hist2, rem1, sel2, rem2);
  hipLaunchKernelGGL(hist_l3, dim3(1024), dim3(256), 0, stream, c1, sel1, sel2, hist3);
  hipLaunchKernelGGL(scan_l3, dim3(1), dim3(1024), 0, stream, hist3, sel1, sel2, rem2, scal);
  hipLaunchKernelGGL(init_cost, dim3(4096), dim3(256), 0, stream, gray, c1, scal, c1, c2);

  int dev=0; (void)hipGetDevice(&dev);
  int cus=0; (void)hipDeviceGetAttribute(&cus, hipDeviceAttributeMultiprocessorCount, dev);
  int nb=0;  (void)hipOccupancyMaxActiveBlocksPerMultiprocessor(&nb, ws_solve, 256, 0);
  if (cus<=0) cus=256;
  if (nb<=0) nb=1;
  long long gmax=(long long)nb*(long long)cus;
  int grid=(int)((gmax<NTILES)?gmax:NTILES);
  void* args[]={ (void*)&c1,(void*)&c2,(void*)&gray,(void*)&flags,(void*)&dirty0,(void*)&dirty1 };
  (void)hipLaunchCooperativeKernel(ws_solve, dim3(grid), dim3(256), args, 0, stream);

  hipLaunchKernelGGL(out_kernel, dim3(4096), dim3(256), 0, stream, c1, out);
}

// Round 3
// 2449.436 us; speedup vs baseline: 1.5482x; 1.5482x over previous
//
#include <hip/hip_runtime.h>
#include <hip/hip_cooperative_groups.h>

#define HH 2048
#define WW 2048
#define NPX (HH*WW)
#define INFV 1e30f
#define TS 128        /* tile size for persistent solver */
#define NT 16         /* tiles per dimension */
#define NTL 256       /* total tiles = blocks */

namespace cg = cooperative_groups;

// ---------- shared math (pinned rounding so every pass computes identical fr) ----------
__device__ __forceinline__ float sobel_at(const float* __restrict__ g, int y, int x){
  float a00,a01,a02,a10,a12,a20,a21,a22;
  if (y>0 && y<HH-1 && x>0 && x<WW-1){
    const float* p = g + (size_t)(y-1)*WW + x;
    a00=p[-1]; a01=p[0]; a02=p[1];
    p += WW;   a10=p[-1];          a12=p[1];
    p += WW;   a20=p[-1]; a21=p[0]; a22=p[1];
  } else {
    auto at=[&](int yy,int xx)->float{
      return (yy<0||yy>=HH||xx<0||xx>=WW)?0.0f:g[(size_t)yy*WW+xx];
    };
    a00=at(y-1,x-1); a01=at(y-1,x); a02=at(y-1,x+1);
    a10=at(y,  x-1);                a12=at(y,  x+1);
    a20=at(y+1,x-1); a21=at(y+1,x); a22=at(y+1,x+1);
  }
  float gx = __fadd_rn(__fadd_rn(__fsub_rn(a02,a00), __fmul_rn(2.0f,__fsub_rn(a12,a10))), __fsub_rn(a22,a20));
  float gy = __fadd_rn(__fadd_rn(__fsub_rn(a20,a00), __fmul_rn(2.0f,__fsub_rn(a21,a01))), __fsub_rn(a22,a02));
  return sqrtf(__fadd_rn(__fmul_rn(gx,gx),__fmul_rn(gy,gy)));
}

// ---------- gray ----------
__global__ void gray_kernel(const float* __restrict__ img, float* __restrict__ gray){
  const float* R=img; const float* G=img+NPX; const float* B=img+2*(size_t)NPX;
  for (int i=blockIdx.x*blockDim.x+threadIdx.x; i<NPX; i+=gridDim.x*blockDim.x){
    gray[i] = __fadd_rn(__fadd_rn(__fmul_rn(0.2989f,R[i]),__fmul_rn(0.587f,G[i])),__fmul_rn(0.114f,B[i]));
  }
}

// ---------- sobel once, cached to fr; level-1 histogram fused ----------
__global__ void sobel_hist1(const float* __restrict__ gray, float* __restrict__ fr,
                            unsigned* __restrict__ hist){
  __shared__ unsigned h[4*2048];
  for (int i=threadIdx.x;i<4*2048;i+=blockDim.x) h[i]=0;
  __syncthreads();
  const int rep=(threadIdx.x&3)*2048;
  for (int i=blockIdx.x*blockDim.x+threadIdx.x; i<NPX; i+=gridDim.x*blockDim.x){
    int y=i>>11, x=i&(WW-1);
    float f=sobel_at(gray,y,x);
    fr[i]=f;
    unsigned key=__float_as_uint(f);
    atomicAdd(&h[rep+(key>>21)],1u);
  }
  __syncthreads();
  for (int i=threadIdx.x;i<2048;i+=blockDim.x){
    unsigned s=h[i]+h[i+2048]+h[i+4096]+h[i+6144];
    if (s) atomicAdd(&hist[i],s);
  }
}

__global__ void hist_l2(const float* __restrict__ fr, const unsigned* __restrict__ sel1,
                        unsigned* __restrict__ hist2){
  __shared__ unsigned h[4*2048];
  __shared__ unsigned sb[4];
  if (threadIdx.x<4) sb[threadIdx.x]=sel1[threadIdx.x];
  for (int i=threadIdx.x;i<4*2048;i+=blockDim.x) h[i]=0;
  __syncthreads();
  for (int i=blockIdx.x*blockDim.x+threadIdx.x; i<NPX; i+=gridDim.x*blockDim.x){
    unsigned key=__float_as_uint(fr[i]);
    unsigned b=key>>21, sub=(key>>10)&0x7FFu;
    #pragma unroll
    for (int k=0;k<4;++k) if (b==sb[k]) atomicAdd(&h[k*2048+sub],1u);
  }
  __syncthreads();
  for (int i=threadIdx.x;i<4*2048;i+=blockDim.x){ unsigned s=h[i]; if (s) atomicAdd(&hist2[i],s); }
}

__global__ void hist_l3(const float* __restrict__ fr, const unsigned* __restrict__ sel1,
                        const unsigned* __restrict__ sel2, unsigned* __restrict__ hist3){
  __shared__ unsigned h[4*1024];
  __shared__ unsigned pf[4];
  if (threadIdx.x<4) pf[threadIdx.x]=(sel1[threadIdx.x]<<11)|sel2[threadIdx.x];
  for (int i=threadIdx.x;i<4*1024;i+=blockDim.x) h[i]=0;
  __syncthreads();
  for (int i=blockIdx.x*blockDim.x+threadIdx.x; i<NPX; i+=gridDim.x*blockDim.x){
    unsigned key=__float_as_uint(fr[i]);
    unsigned p22=key>>10, sub=key&0x3FFu;
    #pragma unroll
    for (int k=0;k<4;++k) if (p22==pf[k]) atomicAdd(&h[k*1024+sub],1u);
  }
  __syncthreads();
  for (int i=threadIdx.x;i<4*1024;i+=blockDim.x){ unsigned s=h[i]; if (s) atomicAdd(&hist3[i],s); }
}

// ranks: floor(0.9825*(n-1))=4120902, floor(0.9925*(n-1))=4162845 (and +1 each)
__global__ void scan_l1(const unsigned* __restrict__ hist, unsigned* __restrict__ sel1,
                        unsigned* __restrict__ rem1){
  __shared__ unsigned part[1024];
  const int t=threadIdx.x;
  unsigned a=hist[2*t], b=hist[2*t+1];
  part[t]=a+b; __syncthreads();
  for (int off=1;off<1024;off<<=1){
    unsigned add=(t>=off)?part[t-off]:0u; __syncthreads();
    part[t]+=add; __syncthreads();
  }
  unsigned before=(t>0)?part[t-1]:0u;
  const unsigned R[4]={4120902u,4120903u,4162845u,4162846u};
  unsigned cum=before;
  #pragma unroll
  for (int i=0;i<4;++i) if (R[i]>=cum && R[i]<cum+a){ sel1[i]=2*t;   rem1[i]=R[i]-cum; }
  cum+=a;
  #pragma unroll
  for (int i=0;i<4;++i) if (R[i]>=cum && R[i]<cum+b){ sel1[i]=2*t+1; rem1[i]=R[i]-cum; }
}

__global__ void scan_l2(const unsigned* __restrict__ hist2, const unsigned* __restrict__ rem1,
                        unsigned* __restrict__ sel2, unsigned* __restrict__ rem2){
  __shared__ unsigned part[1024];
  const int t=threadIdx.x;
  for (int i=0;i<4;++i){
    const unsigned* hh=hist2+i*2048;
    unsigned a=hh[2*t], b=hh[2*t+1];
    part[t]=a+b; __syncthreads();
    for (int off=1;off<1024;off<<=1){
      unsigned add=(t>=off)?part[t-off]:0u; __syncthreads();
      part[t]+=add; __syncthreads();
    }
    unsigned before=(t>0)?part[t-1]:0u;
    unsigned r=rem1[i], cum=before;
    if (r>=cum && r<cum+a){ sel2[i]=2*t;   rem2[i]=r-cum; }
    cum+=a;
    if (r>=cum && r<cum+b){ sel2[i]=2*t+1; rem2[i]=r-cum; }
    __syncthreads();
  }
}

__global__ void scan_l3(const unsigned* __restrict__ hist3, const unsigned* __restrict__ sel1,
                        const unsigned* __restrict__ sel2, const unsigned* __restrict__ rem2,
                        float* __restrict__ scal){
  __shared__ unsigned part[1024];
  __shared__ float vals[4];
  const int t=threadIdx.x;
  for (int i=0;i<4;++i){
    unsigned c=hist3[i*1024+t];
    part[t]=c; __syncthreads();
    for (int off=1;off<1024;off<<=1){
      unsigned add=(t>=off)?part[t-off]:0u; __syncthreads();
      part[t]+=add; __syncthreads();
    }
    unsigned before=(t>0)?part[t-1]:0u;
    unsigned r=rem2[i];
    if (r>=before && r<before+c){
      unsigned key=(sel1[i]<<21)|(sel2[i]<<10)|(unsigned)t;
      vals[i]=__uint_as_float(key);
    }
    __syncthreads();
  }
  if (t==0){
    scal[0]=__fadd_rn(__fmul_rn(vals[0],0.25f),__fmul_rn(vals[1],0.75f));
    scal[1]=__fadd_rn(__fmul_rn(vals[2],0.25f),__fmul_rn(vals[3],0.75f));
  }
}

// ---------- markers -> initial costs (fr aliases c1out; per-element read-then-write) ----------
__global__ void init_cost(const float* __restrict__ gray, const float* frbuf,
                          const float* __restrict__ scal,
                          float* c1out, float* __restrict__ c2out){
  const float qlo=scal[0], qhi=scal[1];
  for (int i=blockIdx.x*blockDim.x+threadIdx.x; i<NPX; i+=gridDim.x*blockDim.x){
    float f=frbuf[i];
    float g=gray[i];
    bool m1 = (f<=qlo);
    bool m2 = (!m1) && (f>=qhi);
    c1out[i] = m1 ? g : INFV;
    c2out[i] = m2 ? g : INFV;
  }
}

// ---------- persistent-tile cooperative fixed-point solver ----------
// clamp composition: f_cur(f_prev(v)) with f=(lo,hi)->min(hi,max(lo,v)):
//   hi' = min(hi_cur, max(lo_cur, hi_prev)); lo' = max(lo_cur, lo_prev)

#define HSCAN_LR(va,vb,gA,gB,hl) do{ \
  float ql_=gA[j], qh_=va[j]; \
  qh_=fminf(vb[j],fmaxf(gB[j],qh_)); ql_=fmaxf(gB[j],ql_); \
  _Pragma("unroll") \
  for (int d_=1;d_<64;d_<<=1){ \
    float pl_=__shfl_up(ql_,(unsigned)d_), ph_=__shfl_up(qh_,(unsigned)d_); \
    if (c>=d_){ qh_=fminf(qh_,fmaxf(ql_,ph_)); ql_=fmaxf(ql_,pl_); } \
  } \
  float E_=fminf(qh_,fmaxf(ql_,(hl))); \
  float In_=__shfl_up(E_,1u); if(c==0) In_=(hl); \
  float na_=fminf(va[j],fmaxf(gA[j],In_)); if(na_<va[j]){va[j]=na_;ch=true;} \
  float nb_=fminf(vb[j],fmaxf(gB[j],na_)); if(nb_<vb[j]){vb[j]=nb_;ch=true;} \
}while(0)

#define HSCAN_RL(va,vb,gA,gB,hr) do{ \
  float ql_=gB[j], qh_=vb[j]; \
  qh_=fminf(va[j],fmaxf(gA[j],qh_)); ql_=fmaxf(gA[j],ql_); \
  _Pragma("unroll") \
  for (int d_=1;d_<64;d_<<=1){ \
    float pl_=__shfl_down(ql_,(unsigned)d_), ph_=__shfl_down(qh_,(unsigned)d_); \
    if (c+d_<64){ qh_=fminf(qh_,fmaxf(ql_,ph_)); ql_=fmaxf(ql_,pl_); } \
  } \
  float E_=fminf(qh_,fmaxf(ql_,(hr))); \
  float In_=__shfl_down(E_,1u); if(c==63) In_=(hr); \
  float nb_=fminf(vb[j],fmaxf(gB[j],In_)); if(nb_<vb[j]){vb[j]=nb_;ch=true;} \
  float na_=fminf(va[j],fmaxf(gA[j],nb_)); if(na_<va[j]){va[j]=na_;ch=true;} \
}while(0)

#define VCOMP_DN(va,gA,Larr,Harr,XX) { float ql_=gA[0], qh_=va[0]; \
  _Pragma("unroll") for (int jj_=1;jj_<8;++jj_){ qh_=fminf(va[jj_],fmaxf(gA[jj_],qh_)); ql_=fmaxf(gA[jj_],ql_);} \
  Larr[w][XX]=ql_; Harr[w][XX]=qh_; }

#define VCOMP_UP(va,gA,Larr,Harr,XX) { float ql_=gA[7], qh_=va[7]; \
  _Pragma("unroll") for (int jj_=6;jj_>=0;--jj_){ qh_=fminf(va[jj_],fmaxf(gA[jj_],qh_)); ql_=fmaxf(gA[jj_],ql_);} \
  Larr[w][XX]=ql_; Harr[w][XX]=qh_; }

#define VAPPLY_DN(va,gA,Larr,XX) { float In_=Larr[w][XX]; \
  _Pragma("unroll") for (int jj_=0;jj_<8;++jj_){ float nv_=fminf(va[jj_],fmaxf(In_,gA[jj_])); if(nv_<va[jj_]){va[jj_]=nv_;ch=true;} In_=nv_; } }

#define VAPPLY_UP(va,gA,Larr,XX) { float In_=Larr[w][XX]; \
  _Pragma("unroll") for (int jj_=7;jj_>=0;--jj_){ float nv_=fminf(va[jj_],fmaxf(In_,gA[jj_])); if(nv_<va[jj_]){va[jj_]=nv_;ch=true;} In_=nv_; } }

__global__ void __launch_bounds__(1024,4)
ws_solve(float* __restrict__ c1g, const float* __restrict__ grayg, float* outg,
         int* __restrict__ flagIt, int* __restrict__ chg)
{
  __shared__ float DL1[16][128], DH1[16][128], DL2[16][128], DH2[16][128];
  __shared__ float Ht1[128],Ht2[128],Hb1[128],Hb2[128],Hl1[128],Hl2[128],Hr1[128],Hr2[128];
  __shared__ int cflag[2];
  __shared__ int sneed;
  cg::grid_group grid = cg::this_grid();
  const int tid=threadIdx.x, w=tid>>6, c=tid&63;
  const int tile=blockIdx.x, ty=tile>>4, tx=tile&15;
  const int by=ty*TS, bx=tx*TS, x0=c<<1;
  float* EB1=outg;
  float* EB2=outg+(NTL*4*128);

  float v1a[8],v1b[8],v2a[8],v2b[8],ga[8],gb[8];
  {
    size_t base=(size_t)(by+(w<<3))*WW + bx + x0;
    #pragma unroll
    for (int j=0;j<8;++j){
      float2 t1=*(const float2*)(c1g+base);
      float2 t2=*(const float2*)(outg+base);   // c2 initial lives in d_out
      float2 tg=*(const float2*)(grayg+base);
      v1a[j]=t1.x; v1b[j]=t1.y; v2a[j]=t2.x; v2b[j]=t2.y; ga[j]=tg.x; gb[j]=tg.y;
      base+=(size_t)WW;
    }
  }
  grid.sync();   // all c2 loads complete before edge buffers overwrite d_out

  for (int it=0; it<512; ++it){
    if (tid==0){
      int need=1;
      if (it>=2){
        need=0;
        if (ty>0)             need |= (__hip_atomic_load(&chg[tile-NT],__ATOMIC_RELAXED,__HIP_MEMORY_SCOPE_AGENT) >= it-1);
        if (!need && ty<NT-1) need |= (__hip_atomic_load(&chg[tile+NT],__ATOMIC_RELAXED,__HIP_MEMORY_SCOPE_AGENT) >= it-1);
        if (!need && tx>0)    need |= (__hip_atomic_load(&chg[tile-1],__ATOMIC_RELAXED,__HIP_MEMORY_SCOPE_AGENT) >= it-1);
        if (!need && tx<NT-1) need |= (__hip_atomic_load(&chg[tile+1],__ATOMIC_RELAXED,__HIP_MEMORY_SCOPE_AGENT) >= it-1);
      }
      sneed=need;
    }
    __syncthreads();
    bool bany=false;
    if (sneed){
      { // halos: 1024 threads -> 8 arrays x 128 entries; it==0 uses INF (Jacobi-safe)
        const int x=tid&127, arr=tid>>7;
        float vI=INFV;
        if (it>0){
          const float* EB=(arr&1)?EB2:EB1;
          switch(arr>>1){
            case 0: if (ty>0)    vI=EB[((tile-NT)*4+1)*128+x]; break;
            case 1: if (ty<NT-1) vI=EB[((tile+NT)*4+0)*128+x]; break;
            case 2: if (tx>0)    vI=EB[((tile-1)*4+3)*128+x]; break;
            default:if (tx<NT-1) vI=EB[((tile+1)*4+2)*128+x]; break;
          }
        }
        switch(arr){
          case 0: Ht1[x]=vI; break; case 1: Ht2[x]=vI; break;
          case 2: Hb1[x]=vI; break; case 3: Hb2[x]=vI; break;
          case 4: Hl1[x]=vI; break; case 5: Hl2[x]=vI; break;
          case 6: Hr1[x]=vI; break; default: Hr2[x]=vI; break;
        }
      }
      if (tid==0){ cflag[0]=0; cflag[1]=0; }
      __syncthreads();
      for (int cyc=0; cyc<256; ++cyc){
        bool ch=false;
        // ---- vertical down: band compose -> cross-band chain -> apply ----
        VCOMP_DN(v1a,ga,DL1,DH1,x0)   VCOMP_DN(v1b,gb,DL1,DH1,x0+1)
        VCOMP_DN(v2a,ga,DL2,DH2,x0)   VCOMP_DN(v2b,gb,DL2,DH2,x0+1)
        __syncthreads();
        if (w<4){
          const int s=(w<<6)|c, x=s&127; const bool f2=(s>=128);
          float lo[16],hi[16];
          if (f2){
            #pragma unroll
            for (int b=0;b<16;++b){ lo[b]=DL2[b][x]; hi[b]=DH2[b][x]; }
            float E=Ht2[x];
            #pragma unroll
            for (int b=0;b<16;++b){ float I=E; E=fminf(hi[b],fmaxf(lo[b],I)); DL2[b][x]=I; }
          } else {
            #pragma unroll
            for (int b=0;b<16;++b){ lo[b]=DL1[b][x]; hi[b]=DH1[b][x]; }
            float E=Ht1[x];
            #pragma unroll
            for (int b=0;b<16;++b){ float I=E; E=fminf(hi[b],fmaxf(lo[b],I)); DL1[b][x]=I; }
          }
        }
        __syncthreads();
        VAPPLY_DN(v1a,ga,DL1,x0)   VAPPLY_DN(v1b,gb,DL1,x0+1)
        VAPPLY_DN(v2a,ga,DL2,x0)   VAPPLY_DN(v2b,gb,DL2,x0+1)
        // ---- vertical up (reuse arrays; own-entry writes, chain waves past barrier) ----
        VCOMP_UP(v1a,ga,DL1,DH1,x0)   VCOMP_UP(v1b,gb,DL1,DH1,x0+1)
        VCOMP_UP(v2a,ga,DL2,DH2,x0)   VCOMP_UP(v2b,gb,DL2,DH2,x0+1)
        __syncthreads();
        if (w<4){
          const int s=(w<<6)|c, x=s&127; const bool f2=(s>=128);
          float lo[16],hi[16];
          if (f2){
            #pragma unroll
            for (int b=0;b<16;++b){ lo[b]=DL2[b][x]; hi[b]=DH2[b][x]; }
            float E=Hb2[x];
            #pragma unroll
            for (int b=15;b>=0;--b){ float I=E; E=fminf(hi[b],fmaxf(lo[b],I)); DL2[b][x]=I; }
          } else {
            #pragma unroll
            for (int b=0;b<16;++b){ lo[b]=DL1[b][x]; hi[b]=DH1[b][x]; }
            float E=Hb1[x];
            #pragma unroll
            for (int b=15;b>=0;--b){ float I=E; E=fminf(hi[b],fmaxf(lo[b],I)); DL1[b][x]=I; }
          }
        }
        __syncthreads();
        VAPPLY_UP(v1a,ga,DL1,x0)   VAPPLY_UP(v1b,gb,DL1,x0+1)
        VAPPLY_UP(v2a,ga,DL2,x0)   VAPPLY_UP(v2b,gb,DL2,x0+1)
        // ---- horizontal: probe + clamp-compose wave scans (rows wave-local) ----
        #pragma unroll
        for (int j=0;j<8;++j){
          const int r=(w<<3)|j;
          const float hl1=Hl1[r],hr1=Hr1[r],hl2=Hl2[r],hr2=Hr2[r];
          float la1=__shfl_up(v1b[j],1u);   if(c==0)  la1=hl1;
          float ra1=__shfl_down(v1a[j],1u); if(c==63) ra1=hr1;
          float la2=__shfl_up(v2b[j],1u);   if(c==0)  la2=hl2;
          float ra2=__shfl_down(v2a[j],1u); if(c==63) ra2=hr2;
          bool rc=(fminf(v1a[j],fmaxf(fminf(la1,v1b[j]),ga[j]))<v1a[j])
                ||(fminf(v1b[j],fmaxf(fminf(v1a[j],ra1),gb[j]))<v1b[j])
                ||(fminf(v2a[j],fmaxf(fminf(la2,v2b[j]),ga[j]))<v2a[j])
                ||(fminf(v2b[j],fmaxf(fminf(v2a[j],ra2),gb[j]))<v2b[j]);
          if (__any(rc)){
            HSCAN_LR(v1a,v1b,ga,gb,hl1);
            HSCAN_LR(v2a,v2b,ga,gb,hl2);
            HSCAN_RL(v1a,v1b,ga,gb,hr1);
            HSCAN_RL(v2a,v2b,ga,gb,hr2);
          }
        }
        if (ch) cflag[cyc&1]=1;
        __syncthreads();
        const int f=cflag[cyc&1];
        if (tid==0) cflag[(cyc+1)&1]=0;
        if (f) bany=true; else break;
      }
      if (bany || it==0){
        // publish boundary edges
        if (w==0){
          const int eb=(tile*4+0)*128;
          EB1[eb+x0]=v1a[0]; EB1[eb+x0+1]=v1b[0];
          EB2[eb+x0]=v2a[0]; EB2[eb+x0+1]=v2b[0];
        }
        if (w==15){
          const int eb=(tile*4+1)*128;
          EB1[eb+x0]=v1a[7]; EB1[eb+x0+1]=v1b[7];
          EB2[eb+x0]=v2a[7]; EB2[eb+x0+1]=v2b[7];
        }
        if (c==0){
          const int eb=(tile*4+2)*128+(w<<3);
          #pragma unroll
          for (int j=0;j<8;++j){ EB1[eb+j]=v1a[j]; EB2[eb+j]=v2a[j]; }
        }
        if (c==63){
          const int eb=(tile*4+3)*128+(w<<3);
          #pragma unroll
          for (int j=0;j<8;++j){ EB1[eb+j]=v1b[j]; EB2[eb+j]=v2b[j]; }
        }
        if (tid==0){
          if (bany) __hip_atomic_store(&chg[tile],it,__ATOMIC_RELAXED,__HIP_MEMORY_SCOPE_AGENT);
          atomicMax(flagIt,it);
        }
      }
    }
    __threadfence();
    grid.sync();
    if (it>=1){
      int fv=__hip_atomic_load(flagIt,__ATOMIC_RELAXED,__HIP_MEMORY_SCOPE_AGENT);
      if (fv<it) break;   // uniform: monotone stamps, no resets needed
    }
  }
  // fused label output: out = (c2 < c1) ? 1 : 0
  {
    size_t base=(size_t)(by+(w<<3))*WW + bx + x0;
    #pragma unroll
    for (int j=0;j<8;++j){
      float2 o; o.x=(v2a[j]<v1a[j])?1.0f:0.0f; o.y=(v2b[j]<v1b[j])?1.0f:0.0f;
      *(float2*)(outg+base)=o;
      base+=(size_t)WW;
    }
  }
}

extern "C" void kernel_launch(void* const* d_in, const int* in_sizes, int n_in,
                              void* d_out, int out_size, void* d_ws, size_t ws_size,
                              hipStream_t stream)
{
  const float* img=(const float*)d_in[0];
  float* out=(float*)d_out;
  char* wsb=(char*)d_ws;
  float* gray=(float*)wsb;
  float* c1  =(float*)(wsb + (size_t)NPX*4);   // doubles as fr cache before init_cost
  unsigned* meta=(unsigned*)(wsb + (size_t)NPX*8);
  float* c2 = out;   // c2 initial state lives in d_out (fully rewritten each launch)

  unsigned* hist1=meta;            // 2048
  unsigned* hist2=meta+2048;       // 4*2048
  unsigned* hist3=meta+10240;      // 4*1024
  unsigned* sel1 =meta+14336;
  unsigned* rem1 =meta+14340;
  unsigned* sel2 =meta+14344;
  unsigned* rem2 =meta+14348;
  float*    scal =(float*)(meta+14352);   // 2
  int*      flagIt=(int*)(meta+14354);    // 1
  int*      chg  =(int*)(meta+14355);     // 256  -> total 14611 u32

  hipMemsetAsync(meta, 0, 14611*sizeof(unsigned), stream);
  hipLaunchKernelGGL(gray_kernel, dim3(4096), dim3(256), 0, stream, img, gray);
  hipLaunchKernelGGL(sobel_hist1, dim3(1024), dim3(256), 0, stream, gray, c1, hist1);
  hipLaunchKernelGGL(scan_l1, dim3(1), dim3(1024), 0, stream, hist1, sel1, rem1);
  hipLaunchKernelGGL(hist_l2, dim3(1024), dim3(256), 0, stream, c1, sel1, hist2);
  hipLaunchKernelGGL(scan_l2, dim3(1), dim3(1024), 0, stream, hist2, rem1, sel2, rem2);
  hipLaunchKernelGGL(hist_l3, dim3(1024), dim3(256), 0, stream, c1, sel1, sel2, hist3);
  hipLaunchKernelGGL(scan_l3, dim3(1), dim3(1024), 0, stream, hist3, sel1, sel2, rem2, scal);
  hipLaunchKernelGGL(init_cost, dim3(4096), dim3(256), 0, stream, gray, c1, scal, c1, c2);

  void* args[]={ (void*)&c1,(void*)&gray,(void*)&out,(void*)&flagIt,(void*)&chg };
  (void)hipLaunchCooperativeKernel(ws_solve, dim3(NTL), dim3(1024), args, 0, stream);
}

// Round 4
// 1378.579 us; speedup vs baseline: 2.7509x; 1.7768x over previous
//
#include <hip/hip_runtime.h>
#include <hip/hip_cooperative_groups.h>

#define HH 2048
#define WW 2048
#define NPX (HH*WW)
#define INFV 1e30f
#define TS 128        /* tile size for persistent solver */
#define NT 16         /* tiles per dimension */
#define NTL 256       /* total tiles = blocks */
#define CY 64         /* relax cycles per grid-sync window */

namespace cg = cooperative_groups;

// ---------- shared math (pinned rounding so every pass computes identical fr) ----------
__device__ __forceinline__ float sobel_at(const float* __restrict__ g, int y, int x){
  float a00,a01,a02,a10,a12,a20,a21,a22;
  if (y>0 && y<HH-1 && x>0 && x<WW-1){
    const float* p = g + (size_t)(y-1)*WW + x;
    a00=p[-1]; a01=p[0]; a02=p[1];
    p += WW;   a10=p[-1];          a12=p[1];
    p += WW;   a20=p[-1]; a21=p[0]; a22=p[1];
  } else {
    auto at=[&](int yy,int xx)->float{
      return (yy<0||yy>=HH||xx<0||xx>=WW)?0.0f:g[(size_t)yy*WW+xx];
    };
    a00=at(y-1,x-1); a01=at(y-1,x); a02=at(y-1,x+1);
    a10=at(y,  x-1);                a12=at(y,  x+1);
    a20=at(y+1,x-1); a21=at(y+1,x); a22=at(y+1,x+1);
  }
  float gx = __fadd_rn(__fadd_rn(__fsub_rn(a02,a00), __fmul_rn(2.0f,__fsub_rn(a12,a10))), __fsub_rn(a22,a20));
  float gy = __fadd_rn(__fadd_rn(__fsub_rn(a20,a00), __fmul_rn(2.0f,__fsub_rn(a21,a01))), __fsub_rn(a22,a02));
  return sqrtf(__fadd_rn(__fmul_rn(gx,gx),__fmul_rn(gy,gy)));
}

// ---------- gray ----------
__global__ void gray_kernel(const float* __restrict__ img, float* __restrict__ gray){
  const float* R=img; const float* G=img+NPX; const float* B=img+2*(size_t)NPX;
  for (int i=blockIdx.x*blockDim.x+threadIdx.x; i<NPX; i+=gridDim.x*blockDim.x){
    gray[i] = __fadd_rn(__fadd_rn(__fmul_rn(0.2989f,R[i]),__fmul_rn(0.587f,G[i])),__fmul_rn(0.114f,B[i]));
  }
}

// ---------- sobel once, cached to fr; level-1 histogram fused ----------
__global__ void sobel_hist1(const float* __restrict__ gray, float* __restrict__ fr,
                            unsigned* __restrict__ hist){
  __shared__ unsigned h[4*2048];
  for (int i=threadIdx.x;i<4*2048;i+=blockDim.x) h[i]=0;
  __syncthreads();
  const int rep=(threadIdx.x&3)*2048;
  for (int i=blockIdx.x*blockDim.x+threadIdx.x; i<NPX; i+=gridDim.x*blockDim.x){
    int y=i>>11, x=i&(WW-1);
    float f=sobel_at(gray,y,x);
    fr[i]=f;
    unsigned key=__float_as_uint(f);
    atomicAdd(&h[rep+(key>>21)],1u);
  }
  __syncthreads();
  for (int i=threadIdx.x;i<2048;i+=blockDim.x){
    unsigned s=h[i]+h[i+2048]+h[i+4096]+h[i+6144];
    if (s) atomicAdd(&hist[i],s);
  }
}

__global__ void hist_l2(const float* __restrict__ fr, const unsigned* __restrict__ sel1,
                        unsigned* __restrict__ hist2){
  __shared__ unsigned h[4*2048];
  __shared__ unsigned sb[4];
  if (threadIdx.x<4) sb[threadIdx.x]=sel1[threadIdx.x];
  for (int i=threadIdx.x;i<4*2048;i+=blockDim.x) h[i]=0;
  __syncthreads();
  for (int i=blockIdx.x*blockDim.x+threadIdx.x; i<NPX; i+=gridDim.x*blockDim.x){
    unsigned key=__float_as_uint(fr[i]);
    unsigned b=key>>21, sub=(key>>10)&0x7FFu;
    #pragma unroll
    for (int k=0;k<4;++k) if (b==sb[k]) atomicAdd(&h[k*2048+sub],1u);
  }
  __syncthreads();
  for (int i=threadIdx.x;i<4*2048;i+=blockDim.x){ unsigned s=h[i]; if (s) atomicAdd(&hist2[i],s); }
}

__global__ void hist_l3(const float* __restrict__ fr, const unsigned* __restrict__ sel1,
                        const unsigned* __restrict__ sel2, unsigned* __restrict__ hist3){
  __shared__ unsigned h[4*1024];
  __shared__ unsigned pf[4];
  if (threadIdx.x<4) pf[threadIdx.x]=(sel1[threadIdx.x]<<11)|sel2[threadIdx.x];
  for (int i=threadIdx.x;i<4*1024;i+=blockDim.x) h[i]=0;
  __syncthreads();
  for (int i=blockIdx.x*blockDim.x+threadIdx.x; i<NPX; i+=gridDim.x*blockDim.x){
    unsigned key=__float_as_uint(fr[i]);
    unsigned p22=key>>10, sub=key&0x3FFu;
    #pragma unroll
    for (int k=0;k<4;++k) if (p22==pf[k]) atomicAdd(&h[k*1024+sub],1u);
  }
  __syncthreads();
  for (int i=threadIdx.x;i<4*1024;i+=blockDim.x){ unsigned s=h[i]; if (s) atomicAdd(&hist3[i],s); }
}

// ranks: floor(0.9825*(n-1))=4120902, floor(0.9925*(n-1))=4162845 (and +1 each)
__global__ void scan_l1(const unsigned* __restrict__ hist, unsigned* __restrict__ sel1,
                        unsigned* __restrict__ rem1){
  __shared__ unsigned part[1024];
  const int t=threadIdx.x;
  unsigned a=hist[2*t], b=hist[2*t+1];
  part[t]=a+b; __syncthreads();
  for (int off=1;off<1024;off<<=1){
    unsigned add=(t>=off)?part[t-off]:0u; __syncthreads();
    part[t]+=add; __syncthreads();
  }
  unsigned before=(t>0)?part[t-1]:0u;
  const unsigned R[4]={4120902u,4120903u,4162845u,4162846u};
  unsigned cum=before;
  #pragma unroll
  for (int i=0;i<4;++i) if (R[i]>=cum && R[i]<cum+a){ sel1[i]=2*t;   rem1[i]=R[i]-cum; }
  cum+=a;
  #pragma unroll
  for (int i=0;i<4;++i) if (R[i]>=cum && R[i]<cum+b){ sel1[i]=2*t+1; rem1[i]=R[i]-cum; }
}

__global__ void scan_l2(const unsigned* __restrict__ hist2, const unsigned* __restrict__ rem1,
                        unsigned* __restrict__ sel2, unsigned* __restrict__ rem2){
  __shared__ unsigned part[1024];
  const int t=threadIdx.x;
  for (int i=0;i<4;++i){
    const unsigned* hh=hist2+i*2048;
    unsigned a=hh[2*t], b=hh[2*t+1];
    part[t]=a+b; __syncthreads();
    for (int off=1;off<1024;off<<=1){
      unsigned add=(t>=off)?part[t-off]:0u; __syncthreads();
      part[t]+=add; __syncthreads();
    }
    unsigned before=(t>0)?part[t-1]:0u;
    unsigned r=rem1[i], cum=before;
    if (r>=cum && r<cum+a){ sel2[i]=2*t;   rem2[i]=r-cum; }
    cum+=a;
    if (r>=cum && r<cum+b){ sel2[i]=2*t+1; rem2[i]=r-cum; }
    __syncthreads();
  }
}

__global__ void scan_l3(const unsigned* __restrict__ hist3, const unsigned* __restrict__ sel1,
                        const unsigned* __restrict__ sel2, const unsigned* __restrict__ rem2,
                        float* __restrict__ scal){
  __shared__ unsigned part[1024];
  __shared__ float vals[4];
  const int t=threadIdx.x;
  for (int i=0;i<4;++i){
    unsigned c=hist3[i*1024+t];
    part[t]=c; __syncthreads();
    for (int off=1;off<1024;off<<=1){
      unsigned add=(t>=off)?part[t-off]:0u; __syncthreads();
      part[t]+=add; __syncthreads();
    }
    unsigned before=(t>0)?part[t-1]:0u;
    unsigned r=rem2[i];
    if (r>=before && r<before+c){
      unsigned key=(sel1[i]<<21)|(sel2[i]<<10)|(unsigned)t;
      vals[i]=__uint_as_float(key);
    }
    __syncthreads();
  }
  if (t==0){
    scal[0]=__fadd_rn(__fmul_rn(vals[0],0.25f),__fmul_rn(vals[1],0.75f));
    scal[1]=__fadd_rn(__fmul_rn(vals[2],0.25f),__fmul_rn(vals[3],0.75f));
  }
}

// ---------- markers -> initial costs (fr aliases c1out; per-element read-then-write) ----------
__global__ void init_cost(const float* __restrict__ gray, const float* frbuf,
                          const float* __restrict__ scal,
                          float* c1out, float* __restrict__ c2out){
  const float qlo=scal[0], qhi=scal[1];
  for (int i=blockIdx.x*blockDim.x+threadIdx.x; i<NPX; i+=gridDim.x*blockDim.x){
    float f=frbuf[i];
    float g=gray[i];
    bool m1 = (f<=qlo);
    bool m2 = (!m1) && (f>=qhi);
    c1out[i] = m1 ? g : INFV;
    c2out[i] = m2 ? g : INFV;
  }
}

// ---------- persistent-tile cooperative fixed-point solver (free-running halos) ----------
// clamp composition: f_cur(f_prev(v)) with f=(lo,hi)->min(hi,max(lo,v)):
//   hi' = min(hi_cur, max(lo_cur, hi_prev)); lo' = max(lo_cur, lo_prev)

#define HSCAN_LR(va,vb,gA,gB,hl) do{ \
  float ql_=gA[j], qh_=va[j]; \
  qh_=fminf(vb[j],fmaxf(gB[j],qh_)); ql_=fmaxf(gB[j],ql_); \
  _Pragma("unroll") \
  for (int d_=1;d_<64;d_<<=1){ \
    float pl_=__shfl_up(ql_,(unsigned)d_), ph_=__shfl_up(qh_,(unsigned)d_); \
    if (c>=d_){ qh_=fminf(qh_,fmaxf(ql_,ph_)); ql_=fmaxf(ql_,pl_); } \
  } \
  float E_=fminf(qh_,fmaxf(ql_,(hl))); \
  float In_=__shfl_up(E_,1u); if(c==0) In_=(hl); \
  float na_=fminf(va[j],fmaxf(gA[j],In_)); if(na_<va[j]){va[j]=na_;ch=true;} \
  float nb_=fminf(vb[j],fmaxf(gB[j],na_)); if(nb_<vb[j]){vb[j]=nb_;ch=true;} \
}while(0)

#define HSCAN_RL(va,vb,gA,gB,hr) do{ \
  float ql_=gB[j], qh_=vb[j]; \
  qh_=fminf(va[j],fmaxf(gA[j],qh_)); ql_=fmaxf(gA[j],ql_); \
  _Pragma("unroll") \
  for (int d_=1;d_<64;d_<<=1){ \
    float pl_=__shfl_down(ql_,(unsigned)d_), ph_=__shfl_down(qh_,(unsigned)d_); \
    if (c+d_<64){ qh_=fminf(qh_,fmaxf(ql_,ph_)); ql_=fmaxf(ql_,pl_); } \
  } \
  float E_=fminf(qh_,fmaxf(ql_,(hr))); \
  float In_=__shfl_down(E_,1u); if(c==63) In_=(hr); \
  float nb_=fminf(vb[j],fmaxf(gB[j],In_)); if(nb_<vb[j]){vb[j]=nb_;ch=true;} \
  float na_=fminf(va[j],fmaxf(gA[j],nb_)); if(na_<va[j]){va[j]=na_;ch=true;} \
}while(0)

#define VCOMP_DN(va,gA,Larr,Harr,XX) { float ql_=gA[0], qh_=va[0]; \
  _Pragma("unroll") for (int jj_=1;jj_<8;++jj_){ qh_=fminf(va[jj_],fmaxf(gA[jj_],qh_)); ql_=fmaxf(gA[jj_],ql_);} \
  Larr[w][XX]=ql_; Harr[w][XX]=qh_; }

#define VCOMP_UP(va,gA,Larr,Harr,XX) { float ql_=gA[7], qh_=va[7]; \
  _Pragma("unroll") for (int jj_=6;jj_>=0;--jj_){ qh_=fminf(va[jj_],fmaxf(gA[jj_],qh_)); ql_=fmaxf(gA[jj_],ql_);} \
  Larr[w][XX]=ql_; Harr[w][XX]=qh_; }

#define VAPPLY_DN(va,gA,Larr,XX) { float In_=Larr[w][XX]; \
  _Pragma("unroll") for (int jj_=0;jj_<8;++jj_){ float nv_=fminf(va[jj_],fmaxf(In_,gA[jj_])); if(nv_<va[jj_]){va[jj_]=nv_;ch=true;} In_=nv_; } }

#define VAPPLY_UP(va,gA,Larr,XX) { float In_=Larr[w][XX]; \
  _Pragma("unroll") for (int jj_=7;jj_>=0;--jj_){ float nv_=fminf(va[jj_],fmaxf(In_,gA[jj_])); if(nv_<va[jj_]){va[jj_]=nv_;ch=true;} In_=nv_; } }

#define ASTORE(p,v) __hip_atomic_store((p),(v),__ATOMIC_RELAXED,__HIP_MEMORY_SCOPE_AGENT)

__global__ void __launch_bounds__(1024,4)
ws_solve(float* __restrict__ c1g, const float* __restrict__ grayg, float* outg,
         int* __restrict__ flagIt)
{
  __shared__ float DL1[16][128], DH1[16][128], DL2[16][128], DH2[16][128];
  __shared__ float HALO[8][128];   // 0 Ht1,1 Ht2,2 Hb1,3 Hb2,4 Hl1,5 Hl2,6 Hr1,7 Hr2
  __shared__ int F1[2],F2[2],wflag;
  cg::grid_group grid = cg::this_grid();
  const int tid=threadIdx.x, w=tid>>6, c=tid&63;
  const int tile=blockIdx.x, ty=tile>>4, tx=tile&15;
  const int by=ty*TS, bx=tx*TS, x0=c<<1;
  float* EB1=outg;
  float* EB2=outg+(NTL*4*128);

  // this thread's halo-refresh slot (1024 threads <-> 8 arrays x 128 entries)
  const int hx=tid&127, harr=tid>>7;
  const float* hsrc=nullptr;
  {
    const float* EB=(harr&1)?EB2:EB1;
    switch(harr>>1){
      case 0: if (ty>0)    hsrc=EB+((tile-NT)*4+1)*128+hx; break;
      case 1: if (ty<NT-1) hsrc=EB+((tile+NT)*4+0)*128+hx; break;
      case 2: if (tx>0)    hsrc=EB+((tile-1)*4+3)*128+hx;  break;
      default:if (tx<NT-1) hsrc=EB+((tile+1)*4+2)*128+hx;  break;
    }
  }

  float v1a[8],v1b[8],v2a[8],v2b[8],ga[8],gb[8];
  {
    size_t base=(size_t)(by+(w<<3))*WW + bx + x0;
    #pragma unroll
    for (int j=0;j<8;++j){
      float2 t1=*(const float2*)(c1g+base);
      float2 t2=*(const float2*)(outg+base);   // c2 initial lives in d_out
      float2 tg=*(const float2*)(grayg+base);
      v1a[j]=t1.x; v1b[j]=t1.y; v2a[j]=t2.x; v2b[j]=t2.y; ga[j]=tg.x; gb[j]=tg.y;
      base+=(size_t)WW;
    }
  }
  grid.sync();   // all c2 loads complete before edge buffers overwrite d_out
  HALO[harr][hx]=INFV;
  if (tid==0){ F1[0]=1;F2[0]=1;F1[1]=0;F2[1]=0; wflag=0; }

  for (int win=0; win<96; ++win){
    for (int cyc=0; cyc<CY; ++cyc){
      const int cur=cyc&1, nxt=cur^1;
      // (a) free-running halo refresh (monotone-safe stale reads; win0 halo-less)
      if (win>0 && hsrc){
        float nv=__hip_atomic_load(hsrc,__ATOMIC_RELAXED,__HIP_MEMORY_SCOPE_AGENT);
        if (nv < HALO[harr][hx]){
          HALO[harr][hx]=nv;
          if (harr&1) F2[cur]=1; else F1[cur]=1;
        }
      }
      __syncthreads();                         // (b)
      const int r1=F1[cur], r2=F2[cur];
      __syncthreads();                         // (d)
      if (tid==0){ F1[cur]=0; F2[cur]=0; }
      if (!(r1|r2)){
        if (win==0) break;                     // locally converged, no external input possible
        __syncthreads();                       // quiet cycle
        continue;
      }
      bool chf1=false, chf2=false;
      // ---- vertical down: band compose -> cross-band chain -> apply ----
      if (r1){ VCOMP_DN(v1a,ga,DL1,DH1,x0) VCOMP_DN(v1b,gb,DL1,DH1,x0+1) }
      if (r2){ VCOMP_DN(v2a,ga,DL2,DH2,x0) VCOMP_DN(v2b,gb,DL2,DH2,x0+1) }
      __syncthreads();
      if (w<2){ if (r1){
        const int x=(w<<6)|c; float lo[16],hi[16];
        #pragma unroll
        for (int b=0;b<16;++b){ lo[b]=DL1[b][x]; hi[b]=DH1[b][x]; }
        float E=HALO[0][x];
        #pragma unroll
        for (int b=0;b<16;++b){ float I=E; E=fminf(hi[b],fmaxf(lo[b],I)); DL1[b][x]=I; }
      }} else if (w<4){ if (r2){
        const int x=((w&1)<<6)|c; float lo[16],hi[16];
        #pragma unroll
        for (int b=0;b<16;++b){ lo[b]=DL2[b][x]; hi[b]=DH2[b][x]; }
        float E=HALO[1][x];
        #pragma unroll
        for (int b=0;b<16;++b){ float I=E; E=fminf(hi[b],fmaxf(lo[b],I)); DL2[b][x]=I; }
      }}
      __syncthreads();
      if (r1){ bool ch=false;
        VAPPLY_DN(v1a,ga,DL1,x0) VAPPLY_DN(v1b,gb,DL1,x0+1)
        VCOMP_UP(v1a,ga,DL1,DH1,x0) VCOMP_UP(v1b,gb,DL1,DH1,x0+1)
        if (ch) chf1=true; }
      if (r2){ bool ch=false;
        VAPPLY_DN(v2a,ga,DL2,x0) VAPPLY_DN(v2b,gb,DL2,x0+1)
        VCOMP_UP(v2a,ga,DL2,DH2,x0) VCOMP_UP(v2b,gb,DL2,DH2,x0+1)
        if (ch) chf2=true; }
      __syncthreads();
      if (w<2){ if (r1){
        const int x=(w<<6)|c; float lo[16],hi[16];
        #pragma unroll
        for (int b=0;b<16;++b){ lo[b]=DL1[b][x]; hi[b]=DH1[b][x]; }
        float E=HALO[2][x];
        #pragma unroll
        for (int b=15;b>=0;--b){ float I=E; E=fminf(hi[b],fmaxf(lo[b],I)); DL1[b][x]=I; }
      }} else if (w<4){ if (r2){
        const int x=((w&1)<<6)|c; float lo[16],hi[16];
        #pragma unroll
        for (int b=0;b<16;++b){ lo[b]=DL2[b][x]; hi[b]=DH2[b][x]; }
        float E=HALO[3][x];
        #pragma unroll
        for (int b=15;b>=0;--b){ float I=E; E=fminf(hi[b],fmaxf(lo[b],I)); DL2[b][x]=I; }
      }}
      __syncthreads();
      if (r1){ bool ch=false;
        VAPPLY_UP(v1a,ga,DL1,x0) VAPPLY_UP(v1b,gb,DL1,x0+1)
        #pragma unroll
        for (int j=0;j<8;++j){
          const int r=(w<<3)|j;
          const float hl=HALO[4][r], hr=HALO[6][r];
          float la=__shfl_up(v1b[j],1u);   if(c==0)  la=hl;
          float ra=__shfl_down(v1a[j],1u); if(c==63) ra=hr;
          bool rc=(fminf(v1a[j],fmaxf(fminf(la,v1b[j]),ga[j]))<v1a[j])
                ||(fminf(v1b[j],fmaxf(fminf(v1a[j],ra),gb[j]))<v1b[j]);
          if (__any(rc)){ HSCAN_LR(v1a,v1b,ga,gb,hl); HSCAN_RL(v1a,v1b,ga,gb,hr); }
        }
        if (ch) chf1=true; }
      if (r2){ bool ch=false;
        VAPPLY_UP(v2a,ga,DL2,x0) VAPPLY_UP(v2b,gb,DL2,x0+1)
        #pragma unroll
        for (int j=0;j<8;++j){
          const int r=(w<<3)|j;
          const float hl=HALO[5][r], hr=HALO[7][r];
          float la=__shfl_up(v2b[j],1u);   if(c==0)  la=hl;
          float ra=__shfl_down(v2a[j],1u); if(c==63) ra=hr;
          bool rc=(fminf(v2a[j],fmaxf(fminf(la,v2b[j]),ga[j]))<v2a[j])
                ||(fminf(v2b[j],fmaxf(fminf(v2a[j],ra),gb[j]))<v2b[j]);
          if (__any(rc)){ HSCAN_LR(v2a,v2b,ga,gb,hl); HSCAN_RL(v2a,v2b,ga,gb,hr); }
        }
        if (ch) chf2=true; }
      if (chf1){ F1[nxt]=1; wflag=1; }
      if (chf2){ F2[nxt]=1; wflag=1; }
      // publish changed edges (device-scope so other XCDs see them mid-window)
      {
        const bool forced=(win==0)&&(cyc==0);
        const bool p1=chf1||forced, p2=chf2||forced;
        if (p1||p2){
          if (w==0){
            const int eb=(tile*4+0)*128;
            if(p1){ ASTORE(EB1+eb+x0,v1a[0]); ASTORE(EB1+eb+x0+1,v1b[0]); }
            if(p2){ ASTORE(EB2+eb+x0,v2a[0]); ASTORE(EB2+eb+x0+1,v2b[0]); }
          }
          if (w==15){
            const int eb=(tile*4+1)*128;
            if(p1){ ASTORE(EB1+eb+x0,v1a[7]); ASTORE(EB1+eb+x0+1,v1b[7]); }
            if(p2){ ASTORE(EB2+eb+x0,v2a[7]); ASTORE(EB2+eb+x0+1,v2b[7]); }
          }
          if (c==0){
            const int eb=(tile*4+2)*128+(w<<3);
            #pragma unroll
            for (int j=0;j<8;++j){ if(p1)ASTORE(EB1+eb+j,v1a[j]); if(p2)ASTORE(EB2+eb+j,v2a[j]); }
          }
          if (c==63){
            const int eb=(tile*4+3)*128+(w<<3);
            #pragma unroll
            for (int j=0;j<8;++j){ if(p1)ASTORE(EB1+eb+j,v1b[j]); if(p2)ASTORE(EB2+eb+j,v2b[j]); }
          }
        }
      }
      __syncthreads();                         // (h)
    }
    // window end: termination handshake
    if (tid==0 && wflag) atomicMax(flagIt,win);
    __threadfence();
    grid.sync();
    int fv=__hip_atomic_load(flagIt,__ATOMIC_RELAXED,__HIP_MEMORY_SCOPE_AGENT);
    if (fv<win) break;   // a full window with zero changes anywhere -> fixed point
    if (tid==0) wflag=0;
  }
  // fused label output: out = (c2 < c1) ? 1 : 0
  {
    size_t base=(size_t)(by+(w<<3))*WW + bx + x0;
    #pragma unroll
    for (int j=0;j<8;++j){
      float2 o; o.x=(v2a[j]<v1a[j])?1.0f:0.0f; o.y=(v2b[j]<v1b[j])?1.0f:0.0f;
      *(float2*)(outg+base)=o;
      base+=(size_t)WW;
    }
  }
}

extern "C" void kernel_launch(void* const* d_in, const int* in_sizes, int n_in,
                              void* d_out, int out_size, void* d_ws, size_t ws_size,
                              hipStream_t stream)
{
  const float* img=(const float*)d_in[0];
  float* out=(float*)d_out;
  char* wsb=(char*)d_ws;
  float* gray=(float*)wsb;
  float* c1  =(float*)(wsb + (size_t)NPX*4);   // doubles as fr cache before init_cost
  unsigned* meta=(unsigned*)(wsb + (size_t)NPX*8);
  float* c2 = out;   // c2 initial state lives in d_out (fully rewritten each launch)

  unsigned* hist1=meta;            // 2048
  unsigned* hist2=meta+2048;       // 4*2048
  unsigned* hist3=meta+10240;      // 4*1024
  unsigned* sel1 =meta+14336;
  unsigned* rem1 =meta+14340;
  unsigned* sel2 =meta+14344;
  unsigned* rem2 =meta+14348;
  float*    scal =(float*)(meta+14352);   // 2
  int*      flagIt=(int*)(meta+14354);    // 1  -> total 14355 u32

  hipMemsetAsync(meta, 0, 14355*sizeof(unsigned), stream);
  hipLaunchKernelGGL(gray_kernel, dim3(4096), dim3(256), 0, stream, img, gray);
  hipLaunchKernelGGL(sobel_hist1, dim3(1024), dim3(256), 0, stream, gray, c1, hist1);
  hipLaunchKernelGGL(scan_l1, dim3(1), dim3(1024), 0, stream, hist1, sel1, rem1);
  hipLaunchKernelGGL(hist_l2, dim3(1024), dim3(256), 0, stream, c1, sel1, hist2);
  hipLaunchKernelGGL(scan_l2, dim3(1), dim3(1024), 0, stream, hist2, rem1, sel2, rem2);
  hipLaunchKernelGGL(hist_l3, dim3(1024), dim3(256), 0, stream, c1, sel1, sel2, hist3);
  hipLaunchKernelGGL(scan_l3, dim3(1), dim3(1024), 0, stream, hist3, sel1, sel2, rem2, scal);
  hipLaunchKernelGGL(init_cost, dim3(4096), dim3(256), 0, stream, gray, c1, scal, c1, c2);

  void* args[]={ (void*)&c1,(void*)&gray,(void*)&out,(void*)&flagIt };
  (void)hipLaunchCooperativeKernel(ws_solve, dim3(NTL), dim3(1024), args, 0, stream);
}